// Round 3
// baseline (237.235 us; speedup 1.0000x reference)
//
#include <hip/hip_runtime.h>

// Sobel |gx|+|gy|+eps, SAME zero padding. Input (32,1,1024,1024) fp32.
//
// R6: R5 structure with ONE change -- plain (L2-allocating) stores instead of
// __builtin_nontemporal_store.
//
// Rationale (R3/R4/R5 post-mortem): three structurally different kernels
// (reg window, reg pipeline, LDS-DMA + counted vmcnt) ALL land at 84us,
// 2.5 TB/s, VALUBusy ~10%. All 2048 blocks are co-resident (8/CU exactly);
// waves idle on vmcnt while no on-chip pipe is busy. Loads and stores share
// the per-wave vmcnt queue with IN-ORDER retirement, and every kernel
// interleaves ...L,S,L,S...: waiting for a load's data forces the preceding
// nt store to retire first. nt = no-allocate -> store acks from deep in the
// memory path, so every load-consume wait drains a slow HBM write.
// Iteration rate == nt-store retire rate (observed write BW 1.56 TB/s).
// Plain stores ack from L2 (write-back aggregates DRAM writes, decoupled
// from wave progress). Cost: output now allocates in L2/L3 and can evict
// input (FETCH_SIZE expected 73 -> up to ~147 MB) -- a good trade if the
// store gate is real.
//
// Everything else identical to R5:
//  - circular LDS row buffer NB=5 x 4KB = 20KB => 8 blocks/CU
//  - each wave DMAs its 1KB quarter-row via global_load_lds_dwordx4
//  - counted s_waitcnt vmcnt(N) (never 0 in-loop), asm + sched_barrier
//  - halo columns via cndmask, OOB rows zeroed at consume, DMA row clamped
//  - XCD swizzle: same-XCD blocks take 8 adjacent strips (halo L2 reuse)

#define W 1024
#define H 1024
#define R 16          // rows per block strip (64 strips/image)
#define NB 5          // LDS row slots (circular)
#define EPS 1e-5f

typedef float v4f __attribute__((ext_vector_type(4)));

#define WAITVM(n)                                          \
    do {                                                   \
        asm volatile("s_waitcnt vmcnt(" #n ")" ::: "memory"); \
        __builtin_amdgcn_sched_barrier(0);                 \
    } while (0)

#define GLOAD_LDS16(g, l)                                                     \
    __builtin_amdgcn_global_load_lds(                                         \
        (const __attribute__((address_space(1))) void*)(g),                   \
        (__attribute__((address_space(3))) void*)(l), 16, 0, 0)

__global__ __launch_bounds__(256, 8) void sobel_kernel(const float* __restrict__ in,
                                                       float* __restrict__ out) {
    __shared__ float lds[NB * W];   // 20 KB

    const int b = blockIdx.x;                  // 0..2047
    const int t = ((b & 255) << 3) | (b >> 8); // bijective XCD swizzle
    const int img = t >> 6;                    // 64 strips per image
    const int ty = (t & 63) * R;               // first output row of strip
    const int tid = threadIdx.x;
    const int x0 = tid << 2;
    const int wave = tid >> 6;

    const bool t0 = (tid == 0);
    const bool tN = (tid == 255);
    const int cl = t0 ? 0 : (x0 - 4);   // aligned 16B block holding x0-1
    const int cr = tN ? x0 : (x0 + 4);  // aligned 16B block holding x0+4

    const float* base  = in  + (size_t)img * (W * H);
    float*       obase = out + (size_t)img * (W * H);

    // Issue DMA of row y (clamped) into slot s. Wave-uniform LDS dest;
    // HW adds lane*16B -> linear row layout.
    auto dma = [&](int y, int s) {
        const int yc = (y < 0) ? 0 : ((y > H - 1) ? (H - 1) : y);
        const float* g = base + (size_t)yc * W + x0;
        GLOAD_LDS16(g, lds + s * W + (wave << 8));
    };

    // Read row from slot s into d[0..5] = row[x0-1 .. x0+4]; edge lanes and
    // fully-OOB rows (uniform `zero`) repaired with selects.
    auto ldrow = [&](int s, float* d, bool zero) {
        const float* p = lds + s * W;
        v4f A = *(const v4f*)(p + cl);
        v4f M = *(const v4f*)(p + x0);
        v4f C = *(const v4f*)(p + cr);
        float l = t0 ? 0.f : A.w;
        float r = tN ? 0.f : C.x;
        d[0] = zero ? 0.f : l;
        d[1] = zero ? 0.f : M.x;
        d[2] = zero ? 0.f : M.y;
        d[3] = zero ? 0.f : M.z;
        d[4] = zero ? 0.f : M.w;
        d[5] = zero ? 0.f : r;
    };

    // Prologue: DMA rows ty-1 .. ty+2 into slots 0..3 (4 loads in flight).
    dma(ty - 1, 0);
    dma(ty,     1);
    dma(ty + 1, 2);
    dma(ty + 2, 3);

    WAITVM(2);                       // rows ty-1, ty landed
    __builtin_amdgcn_s_barrier();

    float Tw[6], Mw[6], Bw[6];
    ldrow(0, Tw, ty == 0);           // row ty-1 (zero for top strip)
    ldrow(1, Mw, false);             // row ty

#pragma unroll
    for (int i = 0; i < R; ++i) {
        // Wait for row ty+i+1's DMA; newer loads/stores stay in flight.
        if (i == 0)            WAITVM(1);
        else if (i == 1)       WAITVM(2);
        else if (i == R - 1)   WAITVM(2);
        else                   WAITVM(3);
        __builtin_amdgcn_s_barrier();

        // Prefetch row ty+i+3 into slot (i+4)%NB.
        if (i <= R - 3) dma(ty + i + 3, (i + 4) % NB);

        // New bottom row y+1 from LDS slot (i+2)%NB.
        ldrow((i + 2) % NB, Bw, ty + i + 1 >= H);

        v4f o;
#pragma unroll
        for (int j = 0; j < 4; ++j) {
            // Sobel X: [[-1,0,1],[-2,0,2],[-1,0,1]]
            float gx = (Tw[j + 2] - Tw[j]) + 2.0f * (Mw[j + 2] - Mw[j]) + (Bw[j + 2] - Bw[j]);
            // Sobel Y: [[-1,-2,-1],[0,0,0],[1,2,1]]
            float gy = (Bw[j] + 2.0f * Bw[j + 1] + Bw[j + 2]) - (Tw[j] + 2.0f * Tw[j + 1] + Tw[j + 2]);
            o[j] = fabsf(gx) + fabsf(gy) + EPS;
        }
        // R6 change: plain L2-allocating store (was __builtin_nontemporal_store).
        *(v4f*)(obase + (size_t)(ty + i) * W + x0) = o;

#pragma unroll
        for (int j = 0; j < 6; ++j) { Tw[j] = Mw[j]; Mw[j] = Bw[j]; }
    }
}

extern "C" void kernel_launch(void* const* d_in, const int* in_sizes, int n_in,
                              void* d_out, int out_size, void* d_ws, size_t ws_size,
                              hipStream_t stream) {
    const float* x = (const float*)d_in[0];
    float* outp = (float*)d_out;
    const int N = 32;
    dim3 grid(N * (H / R));   // 32 * 64 = 2048 blocks
    dim3 block(256);
    sobel_kernel<<<grid, block, 0, stream>>>(x, outp);
}

// Round 4
// 235.260 us; speedup vs baseline: 1.0084x; 1.0084x over previous
//
#include <hip/hip_runtime.h>

// Sobel |gx|+|gy|+eps, SAME zero padding. Input (32,1,1024,1024) fp32.
//
// R7: forced-depth register pipeline -- inline-asm global loads, no LDS,
// no barriers, hand-counted vmcnt.
//
// R3..R6 post-mortem: four structures all land at 84us / 2.5 TB/s / VALU 9%.
//   R3/R4: no barriers but compiler COLLAPSED the pipeline (VGPR 28/32 <
//          buffer size => loads sunk to first use, depth ~1).
//   R5/R6: real depth via LDS-DMA, but an s_barrier every row re-syncs all
//          32 waves/CU and phase-locks the whole grid (identical code, same
//          launch instant) -> pace set by barrier recurrence, not queue.
// Never tested: deep per-wave MLP with ZERO inter-wave coupling. That is R7.
//
// Mechanism: inline-asm loads are opaque -- the compiler cannot sink them
// (R4's failure) and inserts no vmcnt for their results; waits are mine.
// Per row: 1 aligned dwordx4 (row[x0..x0+3]) + 2 aligned dword halos
// (row[x0-1], row[x0+4]) -- scalars proven innocent by R5/R6. 5 register
// slots (fully unrolled, static indices), loads issued 3 rows ahead of
// consume; steady-state wait vmcnt(8) (never 0 in-loop). Stores are plain
// v4f stores pinned between memory-clobber asms so vmcnt bookkeeping is
// exact (loads and stores share the in-order vmcnt queue):
//   prologue: 15 loads, WAIT(9) -> rows ty-1,ty landed
//   i=0:6  i=1:7  i=2:8  i=3..13:8  i=14:6  i=15:3
// Edge lanes / OOB rows: issue clamped to [0,H-1], zero-fixed with selects
// at consume. XCD swizzle kept. __launch_bounds__(256,6): VGPR cap ~85 so
// the 5x6-float in-flight file fits WITHOUT spill (R4 died at cap 64).

#define W 1024
#define H 1024
#define R 16          // rows per block strip (64 strips/image)
#define EPS 1e-5f

typedef float v4f __attribute__((ext_vector_type(4)));

#define WAITVM(n)                                             \
    do {                                                      \
        asm volatile("s_waitcnt vmcnt(" #n ")" ::: "memory"); \
        __builtin_amdgcn_sched_barrier(0);                    \
    } while (0)

__global__ __launch_bounds__(256, 6) void sobel_kernel(const float* __restrict__ in,
                                                       float* __restrict__ out) {
    const int b = blockIdx.x;                  // 0..2047
    const int t = ((b & 255) << 3) | (b >> 8); // bijective XCD swizzle
    const int img = t >> 6;                    // 64 strips per image
    const int ty = (t & 63) * R;               // first output row of strip
    const int tid = threadIdx.x;
    const int x0 = tid << 2;

    const bool t0 = (tid == 0);
    const bool tN = (tid == 255);
    const unsigned offM = (unsigned)(x0 << 2);             // row[x0]   (16B aligned)
    const unsigned offL = t0 ? 0u : (unsigned)((x0 << 2) - 4);   // row[x0-1]
    const unsigned offR = tN ? 4092u : (unsigned)((x0 << 2) + 16); // row[x0+4]

    const unsigned long long base =
        (unsigned long long)(in + (size_t)img * (size_t)(W * H));
    float* obase = out + (size_t)img * (size_t)(W * H);

    v4f   fm[5];      // row[x0..x0+3] per slot
    float fl[5];      // row[x0-1]
    float fr[5];      // row[x0+4]

    // Issue row yy (clamped) into slot s. s is a compile-time constant after
    // full unroll -> fm/fl/fr stay in registers (rule #20). asm volatile:
    // compiler can neither sink these nor wait on their results.
#define ISSUE(yy, s)                                                     \
    do {                                                                 \
        int yc_ = (yy);                                                  \
        yc_ = yc_ < 0 ? 0 : (yc_ > H - 1 ? H - 1 : yc_);                 \
        const unsigned ro_ = (unsigned)yc_ << 12;                        \
        asm volatile("global_load_dwordx4 %0, %1, %2"                    \
                     : "=v"(fm[s]) : "v"(ro_ + offM), "s"(base) : "memory"); \
        asm volatile("global_load_dword %0, %1, %2"                      \
                     : "=v"(fl[s]) : "v"(ro_ + offL), "s"(base) : "memory"); \
        asm volatile("global_load_dword %0, %1, %2"                      \
                     : "=v"(fr[s]) : "v"(ro_ + offR), "s"(base) : "memory"); \
    } while (0)

    // Consume slot s into d[0..5] = row[x0-1 .. x0+4] with edge/OOB repair.
#define CONSUME(s, zero, d)                                              \
    do {                                                                 \
        const v4f   m_ = fm[s];                                          \
        const float l_ = fl[s];                                          \
        const float r_ = fr[s];                                          \
        const bool  z_ = (zero);                                         \
        d[0] = (z_ || t0) ? 0.f : l_;                                    \
        d[1] = z_ ? 0.f : m_.x;                                          \
        d[2] = z_ ? 0.f : m_.y;                                          \
        d[3] = z_ ? 0.f : m_.z;                                          \
        d[4] = z_ ? 0.f : m_.w;                                          \
        d[5] = (z_ || tN) ? 0.f : r_;                                    \
    } while (0)

    // Prologue: rows ty-1 .. ty+3 into slots 0..4 (15 loads in flight).
    ISSUE(ty - 1, 0);
    ISSUE(ty,     1);
    ISSUE(ty + 1, 2);
    ISSUE(ty + 2, 3);
    ISSUE(ty + 3, 4);

    WAITVM(9);                        // rows ty-1, ty landed
    float Tw[6], Mw[6], Bw[6];
    CONSUME(0, ty == 0, Tw);          // row ty-1 (zero for top strip)
    CONSUME(1, false,   Mw);          // row ty

#pragma unroll
    for (int i = 0; i < R; ++i) {
        const int y = ty + i;

        // Wait for row y+1 (issued 3 iterations back); newer loads and the
        // last 2-3 stores stay in flight. Never 0 in-loop.
        if (i == 0)       WAITVM(6);
        else if (i == 1)  WAITVM(7);
        else if (i <= 13) WAITVM(8);
        else if (i == 14) WAITVM(6);
        else              WAITVM(3);

        // New bottom row y+1 from slot (i+2)%5.
        CONSUME((i + 2) % 5, y + 1 >= H, Bw);

        // Refill: row y+4 into slot i%5 (its old row was consumed at i-2).
        if (i <= 12) ISSUE(y + 4, i % 5);

        v4f o;
#pragma unroll
        for (int j = 0; j < 4; ++j) {
            // Sobel X: [[-1,0,1],[-2,0,2],[-1,0,1]]
            float gx = (Tw[j + 2] - Tw[j]) + 2.0f * (Mw[j + 2] - Mw[j]) + (Bw[j + 2] - Bw[j]);
            // Sobel Y: [[-1,-2,-1],[0,0,0],[1,2,1]]
            float gy = (Bw[j] + 2.0f * Bw[j + 1] + Bw[j + 2]) - (Tw[j] + 2.0f * Tw[j + 1] + Tw[j + 2]);
            o[j] = fabsf(gx) + fabsf(gy) + EPS;
        }
        // Plain store, pinned between memory-clobber asms -> vmcnt counts exact.
        *(v4f*)(obase + (size_t)y * W + x0) = o;

#pragma unroll
        for (int j = 0; j < 6; ++j) { Tw[j] = Mw[j]; Mw[j] = Bw[j]; }
    }
#undef ISSUE
#undef CONSUME
}

extern "C" void kernel_launch(void* const* d_in, const int* in_sizes, int n_in,
                              void* d_out, int out_size, void* d_ws, size_t ws_size,
                              hipStream_t stream) {
    const float* x = (const float*)d_in[0];
    float* outp = (float*)d_out;
    const int N = 32;
    dim3 grid(N * (H / R));   // 32 * 64 = 2048 blocks
    dim3 block(256);
    sobel_kernel<<<grid, block, 0, stream>>>(x, outp);
}